// Round 6
// baseline (374.110 us; speedup 1.0000x reference)
//
#include <hip/hip_runtime.h>

#define SEQ 2048
#define HID 2048
#define NH 16
#define DK 128
#define NTOK 4096  // B*S

typedef __bf16 bf16x8 __attribute__((ext_vector_type(8)));
typedef float f32x4 __attribute__((ext_vector_type(4)));
typedef unsigned int u32x4 __attribute__((ext_vector_type(4)));

__device__ __forceinline__ unsigned short f2bf(float f) {
  unsigned int u = __builtin_bit_cast(unsigned int, f);
  u += 0x7fffu + ((u >> 16) & 1u);
  return (unsigned short)(u >> 16);
}
__device__ __forceinline__ float bf2f(unsigned int lo16) {
  return __builtin_bit_cast(float, lo16 << 16);
}

__device__ __forceinline__ void async_cp16(const void* g, void* l) {
  __builtin_amdgcn_global_load_lds(
      (__attribute__((address_space(1))) void*)const_cast<void*>(g),
      (__attribute__((address_space(3))) void*)l, 16, 0, 0);
}

// ---- fp32 -> bf16 convert (x + 4 weights) + packed bf16 cos/sin table ------
// fcb[s*64+d] = (bf16(cos) | bf16(sin)<<16)
__global__ void convert_all_kernel(const float* __restrict__ x,
                                   const float* __restrict__ wq,
                                   const float* __restrict__ wk,
                                   const float* __restrict__ wv,
                                   const float* __restrict__ wo,
                                   const float* __restrict__ fc,
                                   unsigned short* __restrict__ xb,
                                   unsigned short* __restrict__ wqb,
                                   unsigned short* __restrict__ wkb,
                                   unsigned short* __restrict__ wvb,
                                   unsigned short* __restrict__ wob,
                                   unsigned int* __restrict__ fcb) {
  const int bid = blockIdx.x;
  if (bid >= 24576) {  // fc: 2048 s x 64 d
    const int idx = (bid - 24576) * 256 + threadIdx.x;  // [0, 131072)
    const int s = idx >> 6, d = idx & 63;
    const float2 cs = *(const float2*)(fc + s * 128 + 2 * d);
    fcb[idx] = (unsigned int)f2bf(cs.x) | ((unsigned int)f2bf(cs.y) << 16);
    return;
  }
  const float* src;
  unsigned short* dst;
  int base;
  if (bid < 8192) {               // x: 2,097,152 float4s
    src = x; dst = xb; base = bid;
  } else {
    const int t = (bid - 8192) >> 12;       // 4096 blocks per weight
    base = (bid - 8192) & 4095;
    src = (t == 0) ? wq : (t == 1) ? wk : (t == 2) ? wv : wo;
    dst = (t == 0) ? wqb : (t == 1) ? wkb : (t == 2) ? wvb : wob;
  }
  const int i = base * 256 + threadIdx.x;
  float4 v = ((const float4*)src)[i];
  ushort4 o;
  o.x = f2bf(v.x); o.y = f2bf(v.y); o.z = f2bf(v.z); o.w = f2bf(v.w);
  ((ushort4*)dst)[i] = o;
}

// ---------------- GEMM: C[M,2048] = A[M,2048] * W[2048,2048]^T (BT layout) ----
// 128x128 tile, BK=64, double-buffered LDS, ONE barrier per K-iter:
// barrier -> prefetch(k+1 -> other buffer) -> compute(k). The barrier's
// implicit vmcnt(0) drains loads issued one full body earlier.
// sel 0/1 (Q/K): fused RoPE epilogue (pair partner via shfl_xor lane^1,
// packed bf16 cos/sin table); Q scaled by 1/sqrt(dk). sel 2 (V): transposed.
template<bool F32OUT>
__global__ __launch_bounds__(256, 2)
void gemm_bt_kernel(const unsigned short* __restrict__ A,
                    const unsigned short* __restrict__ B0,
                    const unsigned short* __restrict__ B1,
                    const unsigned short* __restrict__ B2,
                    unsigned short* __restrict__ O0,
                    unsigned short* __restrict__ O1,
                    unsigned short* __restrict__ O2,
                    float* __restrict__ Of,
                    const unsigned int* __restrict__ fcb) {
  __shared__ alignas(16) unsigned short As0[128 * 64];
  __shared__ alignas(16) unsigned short Bs0[128 * 64];
  __shared__ alignas(16) unsigned short As1[128 * 64];
  __shared__ alignas(16) unsigned short Bs1[128 * 64];

  const int bx = blockIdx.x, by = blockIdx.y;
  const unsigned short* B;
  unsigned short* Ob = nullptr;
  int sel = 0, col0;
  if (F32OUT) {
    B = B0;
    col0 = bx * 128;
  } else {
    sel = bx >> 4;
    B = (sel == 0) ? B0 : (sel == 1) ? B1 : B2;
    Ob = (sel == 0) ? O0 : (sel == 1) ? O1 : O2;
    col0 = (bx & 15) * 128;
  }
  const int row0 = by * 128;

  const int tid = threadIdx.x;
  const int wave = tid >> 6, lane = tid & 63;
  const int quad = lane >> 4, r = lane & 15;
  const int wm = wave >> 1, wn = wave & 1;
  const int jbase = wave * 256 + lane;

  f32x4 acc[4][4] = {};

  auto stage = [&](int kt, unsigned short* as, unsigned short* bs) {
    const int k0 = kt * 64;
    for (int t = 0; t < 4; ++t) {
      const int j = jbase + t * 64;         // 0..1023 chunk id
      const int m = j >> 3;                 // tile row 0..127
      const int gc = (j & 7) ^ (m & 7);     // global chunk (swizzled)
      async_cp16(A + (size_t)(row0 + m) * HID + k0 + gc * 8, as + j * 8);
      async_cp16(B + (size_t)(col0 + m) * HID + k0 + gc * 8, bs + j * 8);
    }
  };

  auto body = [&](const unsigned short* as, const unsigned short* bs) {
    for (int kk = 0; kk < 2; ++kk) {
      bf16x8 af[4], bfr[4];
      for (int mt = 0; mt < 4; ++mt) {
        const int m = wm * 64 + mt * 16 + r;
        const int slot = (kk * 4 + quad) ^ (m & 7);
        af[mt] = __builtin_bit_cast(bf16x8, *(const u32x4*)(as + m * 64 + slot * 8));
      }
      for (int nt = 0; nt < 4; ++nt) {
        const int n = wn * 64 + nt * 16 + r;
        const int slot = (kk * 4 + quad) ^ (n & 7);
        bfr[nt] = __builtin_bit_cast(bf16x8, *(const u32x4*)(bs + n * 64 + slot * 8));
      }
      for (int mt = 0; mt < 4; ++mt)
        for (int nt = 0; nt < 4; ++nt)
          acc[mt][nt] = __builtin_amdgcn_mfma_f32_16x16x32_bf16(
              af[mt], bfr[nt], acc[mt][nt], 0, 0, 0);
    }
  };

  const int NK = HID / 64;  // 32, even
  stage(0, As0, Bs0);
  int kt = 0;
  while (true) {
    __syncthreads();                        // drains prefetch from last iter
    if (kt + 1 < NK) stage(kt + 1, As1, Bs1);
    body(As0, Bs0);
    if (++kt == NK) break;
    __syncthreads();
    if (kt + 1 < NK) stage(kt + 1, As0, Bs0);
    body(As1, Bs1);
    if (++kt == NK) break;
  }

  if (!F32OUT && sel == 2) {
    // transposed V write: Vt[(b*2048+col)][s], 4 consecutive tokens per lane
    for (int mt = 0; mt < 4; ++mt) {
      const int row = row0 + wm * 64 + mt * 16 + quad * 4;  // token base
      const int b = row >> 11, s = row & (SEQ - 1);
      for (int nt = 0; nt < 4; ++nt) {
        const int col = col0 + wn * 64 + nt * 16 + r;
        ushort4 pk;
        pk.x = f2bf(acc[mt][nt][0]);
        pk.y = f2bf(acc[mt][nt][1]);
        pk.z = f2bf(acc[mt][nt][2]);
        pk.w = f2bf(acc[mt][nt][3]);
        *(ushort4*)(Ob + ((size_t)(b * HID + col)) * SEQ + s) = pk;
      }
    }
    return;
  }

  if (!F32OUT) {
    // Q/K epilogue with fused RoPE (packed bf16 cos/sin).
    const float qs = (sel == 0) ? 0.08838834764831845f : 1.0f;
    for (int mt = 0; mt < 4; ++mt) {
      const int row = row0 + wm * 64 + mt * 16 + quad * 4;
      for (int nt = 0; nt < 4; ++nt) {
        const int col = col0 + wn * 64 + nt * 16 + r;
        const int d = (wn * 64 + nt * 16 + r) >> 1;
        for (int v = 0; v < 4; ++v) {
          const int s = (row + v) & (SEQ - 1);
          const unsigned int u = fcb[s * 64 + d];
          const float c = bf2f(u & 0xffffu), sn = bf2f(u >> 16);
          const float val = acc[mt][nt][v];
          const float par = __shfl_xor(val, 1, 64);
          const float res = (r & 1) ? (par * sn + val * c)
                                    : (val * c - par * sn);
          Ob[(size_t)(row + v) * HID + col] = f2bf(res * qs);
        }
      }
    }
    return;
  }

  for (int mt = 0; mt < 4; ++mt) {
    const int row = row0 + wm * 64 + mt * 16 + quad * 4;
    for (int nt = 0; nt < 4; ++nt) {
      const int col = col0 + wn * 64 + nt * 16 + r;
      for (int v = 0; v < 4; ++v)
        Of[(size_t)(row + v) * HID + col] = acc[mt][nt][v];
    }
  }
}

// ---------------- Flash attention (causal, online softmax) ------------------
// grid (16, 32): block handles q-tile pair (bx, 31-bx) -> uniform 33 k-tiles.
// Double-buffered K/V, one barrier per k-tile. Row-sum via ones-MFMA.
__global__ __launch_bounds__(256, 2)
void flash_attn_kernel(const unsigned short* __restrict__ Qb,
                       const unsigned short* __restrict__ Kb,
                       const unsigned short* __restrict__ VtG,
                       unsigned short* __restrict__ Ob) {
  __shared__ alignas(16) unsigned short KsA[64 * 128];   // 16 KB
  __shared__ alignas(16) unsigned short KsB[64 * 128];   // 16 KB
  __shared__ alignas(16) unsigned short VsA[128 * 64];   // 16 KB
  __shared__ alignas(16) unsigned short VsB[128 * 64];   // 16 KB
  __shared__ alignas(16) unsigned short Ps[4][16 * 64];  // 8 KB  => 72 KB

  const int bx = blockIdx.x, bh = blockIdx.y;
  const int tid = threadIdx.x, wave = tid >> 6, lane = tid & 63;
  const int quad = lane >> 4, r = lane & 15;
  const int tokbase = (bh >> 4) * SEQ;
  const int h = bh & 15;

  const u32x4 onesv = {0x3F803F80u, 0x3F803F80u, 0x3F803F80u, 0x3F803F80u};

  auto stage = [&](int kt, unsigned short* Ks, unsigned short* Vs) {
    for (int t = 0; t < 4; ++t) {
      const int j = t * 256 + tid;
      const int n = j >> 4, slot = j & 15;
      const int gc = (slot & 8) | ((slot & 7) ^ (n & 7));
      async_cp16(Kb + (size_t)(tokbase + kt * 64 + n) * HID + h * DK + gc * 8,
                 Ks + j * 8);
    }
    for (int t = 0; t < 4; ++t) {
      const int j = t * 256 + tid;
      const int d = j >> 3, slot = j & 7;
      const int gc = slot ^ (d & 7);
      async_cp16(VtG + ((size_t)(bh * DK + d)) * SEQ + kt * 64 + gc * 8,
                 Vs + j * 8);
    }
  };

  for (int phase = 0; phase < 2; ++phase) {
    const int qt = phase ? (31 - bx) : bx;
    const int q0 = qt * 64;

    u32x4 qf[4];
    {
      const unsigned short* qrow =
          Qb + (size_t)(tokbase + q0 + wave * 16 + r) * HID + h * DK;
      for (int kk = 0; kk < 4; ++kk)
        qf[kk] = *(const u32x4*)(qrow + kk * 32 + quad * 8);
    }

    f32x4 o[8] = {};
    float m_i[4], l_i[4];
    for (int v = 0; v < 4; ++v) { m_i[v] = -__builtin_inff(); l_i[v] = 0.f; }

    auto body = [&](const unsigned short* Ks, const unsigned short* Vs, int kt) {
      f32x4 s[4];
      for (int nt = 0; nt < 4; ++nt) {
        f32x4 a = {};
        const int n = nt * 16 + r;
        for (int kk = 0; kk < 4; ++kk) {
          const int c = kk * 4 + quad;
          const int slot = (c & 8) | ((c & 7) ^ (r & 7));
          u32x4 bkf = *(const u32x4*)(Ks + n * 128 + slot * 8);
          a = __builtin_amdgcn_mfma_f32_16x16x32_bf16(
              __builtin_bit_cast(bf16x8, qf[kk]),
              __builtin_bit_cast(bf16x8, bkf), a, 0, 0, 0);
        }
        s[nt] = a;
      }

      if (kt == qt) {
        const int qrow_g = q0 + wave * 16 + quad * 4;
        for (int nt = 0; nt < 4; ++nt) {
          const int col = kt * 64 + nt * 16 + r;
          for (int v = 0; v < 4; ++v)
            if (col > qrow_g + v) s[nt][v] = -__builtin_inff();
        }
      }

      float mx[4];
      for (int v = 0; v < 4; ++v)
        mx[v] = fmaxf(fmaxf(s[0][v], s[1][v]), fmaxf(s[2][v], s[3][v]));
      for (int off = 1; off < 16; off <<= 1)
        for (int v = 0; v < 4; ++v)
          mx[v] = fmaxf(mx[v], __shfl_xor(mx[v], off, 64));

      float alpha[4];
      for (int v = 0; v < 4; ++v) {
        const float mnew = fmaxf(m_i[v], mx[v]);
        alpha[v] = __expf(m_i[v] - mnew);
        m_i[v] = mnew;
      }

      unsigned short* ps = &Ps[wave][0];
      for (int nt = 0; nt < 4; ++nt) {
        const int chunk = nt * 2 + (r >> 3);
        for (int v = 0; v < 4; ++v) {
          const float p = __expf(s[nt][v] - m_i[v]);
          const int row = quad * 4 + v;
          const int slot = chunk ^ (row & 7);
          ps[row * 64 + slot * 8 + (r & 7)] = f2bf(p);
        }
      }
      for (int dt = 0; dt < 8; ++dt)
        for (int v = 0; v < 4; ++v)
          o[dt][v] *= alpha[v];
      __asm__ volatile("" ::: "memory");  // keep P writes before P reads

      f32x4 rsacc = {};
      for (int kk2 = 0; kk2 < 2; ++kk2) {
        const int c = kk2 * 4 + quad;
        const int aslot = c ^ (r & 7);
        u32x4 pa = *(const u32x4*)(ps + r * 64 + aslot * 8);
        rsacc = __builtin_amdgcn_mfma_f32_16x16x32_bf16(
            __builtin_bit_cast(bf16x8, pa),
            __builtin_bit_cast(bf16x8, onesv), rsacc, 0, 0, 0);
        for (int dt = 0; dt < 8; ++dt) {
          const int d = dt * 16 + r;
          const int bslot = c ^ (d & 7);
          u32x4 bv = *(const u32x4*)(Vs + d * 64 + bslot * 8);
          o[dt] = __builtin_amdgcn_mfma_f32_16x16x32_bf16(
              __builtin_bit_cast(bf16x8, pa),
              __builtin_bit_cast(bf16x8, bv), o[dt], 0, 0, 0);
        }
      }
      for (int v = 0; v < 4; ++v)
        l_i[v] = l_i[v] * alpha[v] + rsacc[v];
    };

    stage(0, KsA, VsA);
    int kt = 0;
    while (true) {
      __syncthreads();                        // waits on loads from last iter
      if (kt + 1 <= qt) stage(kt + 1, KsB, VsB);
      body(KsA, VsA, kt);
      if (++kt > qt) break;
      __syncthreads();
      if (kt + 1 <= qt) stage(kt + 1, KsA, VsA);
      body(KsB, VsB, kt);
      if (++kt > qt) break;
    }

    float li[4];
    for (int v = 0; v < 4; ++v) li[v] = 1.f / l_i[v];
    for (int dt = 0; dt < 8; ++dt)
      for (int v = 0; v < 4; ++v) {
        const size_t row = (size_t)tokbase + q0 + wave * 16 + quad * 4 + v;
        Ob[row * HID + h * DK + dt * 16 + r] = f2bf(o[dt][v] * li[v]);
      }
    __syncthreads();  // protect K/V buffers before next phase's prologue stage
  }
}

// ---------------- host ------------------------------------------------------
extern "C" void kernel_launch(void* const* d_in, const int* in_sizes, int n_in,
                              void* d_out, int out_size, void* d_ws, size_t ws_size,
                              hipStream_t stream) {
  const float* x  = (const float*)d_in[0];
  const float* fc = (const float*)d_in[1];
  const float* wq = (const float*)d_in[2];
  const float* wk = (const float*)d_in[3];
  const float* wv = (const float*)d_in[4];
  const float* wo = (const float*)d_in[5];
  float* out = (float*)d_out;

  unsigned short* xb  = (unsigned short*)d_ws;     // [4096][2048]
  unsigned short* wqb = xb  + (size_t)NTOK * HID;  // [2048][2048] each
  unsigned short* wkb = wqb + (size_t)HID * HID;
  unsigned short* wvb = wkb + (size_t)HID * HID;
  unsigned short* wob = wvb + (size_t)HID * HID;
  unsigned short* qb  = wob + (size_t)HID * HID;   // [4096][2048]
  unsigned short* kb  = qb  + (size_t)NTOK * HID;
  unsigned short* vtb = kb  + (size_t)NTOK * HID;  // V^T [32*128][2048]
  unsigned short* ab  = vtb + (size_t)NTOK * HID;  // attn out [4096][2048]
  unsigned int*   fcb = (unsigned int*)(ab + (size_t)NTOK * HID);  // [2048*64]

  convert_all_kernel<<<24576 + 512, 256, 0, stream>>>(
      x, wq, wk, wv, wo, fc, xb, wqb, wkb, wvb, wob, fcb);

  gemm_bt_kernel<false><<<dim3(48, 32), 256, 0, stream>>>(
      xb, wqb, wkb, wvb, qb, kb, vtb, nullptr, fcb);

  flash_attn_kernel<<<dim3(16, 32), 256, 0, stream>>>(qb, kb, vtb, ab);

  gemm_bt_kernel<true><<<dim3(16, 32), 256, 0, stream>>>(
      ab, wob, nullptr, nullptr, nullptr, nullptr, nullptr, out, fcb);
}

// Round 7
// 354.860 us; speedup vs baseline: 1.0542x; 1.0542x over previous
//
#include <hip/hip_runtime.h>

#define SEQ 2048
#define HID 2048
#define NH 16
#define DK 128
#define NTOK 4096  // B*S

typedef __bf16 bf16x8 __attribute__((ext_vector_type(8)));
typedef float f32x4 __attribute__((ext_vector_type(4)));
typedef unsigned int u32x4 __attribute__((ext_vector_type(4)));

__device__ __forceinline__ unsigned short f2bf(float f) {
  unsigned int u = __builtin_bit_cast(unsigned int, f);
  u += 0x7fffu + ((u >> 16) & 1u);
  return (unsigned short)(u >> 16);
}
__device__ __forceinline__ float bf2f(unsigned int lo16) {
  return __builtin_bit_cast(float, lo16 << 16);
}

__device__ __forceinline__ void async_cp16(const void* g, void* l) {
  __builtin_amdgcn_global_load_lds(
      (__attribute__((address_space(1))) void*)const_cast<void*>(g),
      (__attribute__((address_space(3))) void*)l, 16, 0, 0);
}

// ---- fp32 -> bf16 convert (x + 4 weights) + packed bf16 cos/sin table ------
// fcb[s*64+d] = (bf16(cos) | bf16(sin)<<16)
__global__ void convert_all_kernel(const float* __restrict__ x,
                                   const float* __restrict__ wq,
                                   const float* __restrict__ wk,
                                   const float* __restrict__ wv,
                                   const float* __restrict__ wo,
                                   const float* __restrict__ fc,
                                   unsigned short* __restrict__ xb,
                                   unsigned short* __restrict__ wqb,
                                   unsigned short* __restrict__ wkb,
                                   unsigned short* __restrict__ wvb,
                                   unsigned short* __restrict__ wob,
                                   unsigned int* __restrict__ fcb) {
  const int bid = blockIdx.x;
  if (bid >= 24576) {  // fc: 2048 s x 64 d
    const int idx = (bid - 24576) * 256 + threadIdx.x;  // [0, 131072)
    const int s = idx >> 6, d = idx & 63;
    const float2 cs = *(const float2*)(fc + s * 128 + 2 * d);
    fcb[idx] = (unsigned int)f2bf(cs.x) | ((unsigned int)f2bf(cs.y) << 16);
    return;
  }
  const float* src;
  unsigned short* dst;
  int base;
  if (bid < 8192) {               // x: 2,097,152 float4s
    src = x; dst = xb; base = bid;
  } else {
    const int t = (bid - 8192) >> 12;       // 4096 blocks per weight
    base = (bid - 8192) & 4095;
    src = (t == 0) ? wq : (t == 1) ? wk : (t == 2) ? wv : wo;
    dst = (t == 0) ? wqb : (t == 1) ? wkb : (t == 2) ? wvb : wob;
  }
  const int i = base * 256 + threadIdx.x;
  float4 v = ((const float4*)src)[i];
  ushort4 o;
  o.x = f2bf(v.x); o.y = f2bf(v.y); o.z = f2bf(v.z); o.w = f2bf(v.w);
  ((ushort4*)dst)[i] = o;
}

// ---------------- GEMM: C[M,2048] = A[M,2048] * W[2048,2048]^T (BT layout) ----
// 128x128 tile, BK=64, single-buffer LDS (R4-proven config: 32 KB, 2 barriers,
// launch_bounds(256,2) -> MfmaUtil ~45%, ~1000 TF; dbuf variants regress).
// sel 0/1 (Q/K): fused RoPE epilogue (pair partner via shfl_xor lane^1,
// packed bf16 cos/sin table); Q scaled by log2e/sqrt(dk) so flash can use
// exp2. sel 2 (V): transposed bf16 write.
template<bool F32OUT>
__global__ __launch_bounds__(256, 2)
void gemm_bt_kernel(const unsigned short* __restrict__ A,
                    const unsigned short* __restrict__ B0,
                    const unsigned short* __restrict__ B1,
                    const unsigned short* __restrict__ B2,
                    unsigned short* __restrict__ O0,
                    unsigned short* __restrict__ O1,
                    unsigned short* __restrict__ O2,
                    float* __restrict__ Of,
                    const unsigned int* __restrict__ fcb) {
  __shared__ alignas(16) unsigned short As[128 * 64];
  __shared__ alignas(16) unsigned short Bs[128 * 64];

  const int bx = blockIdx.x, by = blockIdx.y;
  const unsigned short* B;
  unsigned short* Ob = nullptr;
  int sel = 0, col0;
  if (F32OUT) {
    B = B0;
    col0 = bx * 128;
  } else {
    sel = bx >> 4;
    B = (sel == 0) ? B0 : (sel == 1) ? B1 : B2;
    Ob = (sel == 0) ? O0 : (sel == 1) ? O1 : O2;
    col0 = (bx & 15) * 128;
  }
  const int row0 = by * 128;

  const int tid = threadIdx.x;
  const int wave = tid >> 6, lane = tid & 63;
  const int quad = lane >> 4, r = lane & 15;
  const int wm = wave >> 1, wn = wave & 1;
  const int jbase = wave * 256 + lane;

  f32x4 acc[4][4] = {};

  for (int k0 = 0; k0 < HID; k0 += 64) {
    for (int t = 0; t < 4; ++t) {
      const int j = jbase + t * 64;         // 0..1023 chunk id
      const int m = j >> 3;                 // tile row 0..127
      const int gc = (j & 7) ^ (m & 7);     // global chunk (swizzled)
      async_cp16(A + (size_t)(row0 + m) * HID + k0 + gc * 8, As + j * 8);
      async_cp16(B + (size_t)(col0 + m) * HID + k0 + gc * 8, Bs + j * 8);
    }
    __syncthreads();
    for (int kk = 0; kk < 2; ++kk) {
      bf16x8 af[4], bfr[4];
      for (int mt = 0; mt < 4; ++mt) {
        const int m = wm * 64 + mt * 16 + r;
        const int slot = (kk * 4 + quad) ^ (m & 7);
        af[mt] = __builtin_bit_cast(bf16x8, *(const u32x4*)(As + m * 64 + slot * 8));
      }
      for (int nt = 0; nt < 4; ++nt) {
        const int n = wn * 64 + nt * 16 + r;
        const int slot = (kk * 4 + quad) ^ (n & 7);
        bfr[nt] = __builtin_bit_cast(bf16x8, *(const u32x4*)(Bs + n * 64 + slot * 8));
      }
      for (int mt = 0; mt < 4; ++mt)
        for (int nt = 0; nt < 4; ++nt)
          acc[mt][nt] = __builtin_amdgcn_mfma_f32_16x16x32_bf16(
              af[mt], bfr[nt], acc[mt][nt], 0, 0, 0);
    }
    __syncthreads();
  }

  if (!F32OUT && sel == 2) {
    // transposed V write: Vt[(b*2048+col)][s], 4 consecutive tokens per lane
    for (int mt = 0; mt < 4; ++mt) {
      const int row = row0 + wm * 64 + mt * 16 + quad * 4;  // token base
      const int b = row >> 11, s = row & (SEQ - 1);
      for (int nt = 0; nt < 4; ++nt) {
        const int col = col0 + wn * 64 + nt * 16 + r;
        ushort4 pk;
        pk.x = f2bf(acc[mt][nt][0]);
        pk.y = f2bf(acc[mt][nt][1]);
        pk.z = f2bf(acc[mt][nt][2]);
        pk.w = f2bf(acc[mt][nt][3]);
        *(ushort4*)(Ob + ((size_t)(b * HID + col)) * SEQ + s) = pk;
      }
    }
    return;
  }

  if (!F32OUT) {
    // Q/K epilogue with fused RoPE (packed bf16 cos/sin).
    // Q also scaled by log2e/sqrt(dk) so flash softmax can use exp2 directly.
    const float qs = (sel == 0) ? 0.12751743f : 1.0f;
    for (int mt = 0; mt < 4; ++mt) {
      const int row = row0 + wm * 64 + mt * 16 + quad * 4;
      for (int nt = 0; nt < 4; ++nt) {
        const int col = col0 + wn * 64 + nt * 16 + r;
        const int d = (wn * 64 + nt * 16 + r) >> 1;
        for (int v = 0; v < 4; ++v) {
          const int s = (row + v) & (SEQ - 1);
          const unsigned int u = fcb[s * 64 + d];
          const float c = bf2f(u & 0xffffu), sn = bf2f(u >> 16);
          const float val = acc[mt][nt][v];
          const float par = __shfl_xor(val, 1, 64);
          const float res = (r & 1) ? (par * sn + val * c)
                                    : (val * c - par * sn);
          Ob[(size_t)(row + v) * HID + col] = f2bf(res * qs);
        }
      }
    }
    return;
  }

  for (int mt = 0; mt < 4; ++mt) {
    const int row = row0 + wm * 64 + mt * 16 + quad * 4;
    for (int nt = 0; nt < 4; ++nt) {
      const int col = col0 + wn * 64 + nt * 16 + r;
      for (int v = 0; v < 4; ++v)
        Of[(size_t)(row + v) * HID + col] = acc[mt][nt][v];
    }
  }
}

// ---------------- Flash attention (causal, online softmax, base-2) ----------
// grid (16, 32): block handles q-tile pair (bx, 31-bx) -> uniform 33 k-tiles.
// Double-buffered K/V, one barrier per k-tile. Row-sum via ones-MFMA.
// Q is pre-scaled by log2e/sqrt(dk) -> softmax in exp2 units.
__global__ __launch_bounds__(256, 2)
void flash_attn_kernel(const unsigned short* __restrict__ Qb,
                       const unsigned short* __restrict__ Kb,
                       const unsigned short* __restrict__ VtG,
                       unsigned short* __restrict__ Ob) {
  __shared__ alignas(16) unsigned short KsA[64 * 128];   // 16 KB
  __shared__ alignas(16) unsigned short KsB[64 * 128];   // 16 KB
  __shared__ alignas(16) unsigned short VsA[128 * 64];   // 16 KB
  __shared__ alignas(16) unsigned short VsB[128 * 64];   // 16 KB
  __shared__ alignas(16) unsigned short Ps[4][16 * 64];  // 8 KB  => 72 KB

  const int bx = blockIdx.x, bh = blockIdx.y;
  const int tid = threadIdx.x, wave = tid >> 6, lane = tid & 63;
  const int quad = lane >> 4, r = lane & 15;
  const int tokbase = (bh >> 4) * SEQ;
  const int h = bh & 15;

  const u32x4 onesv = {0x3F803F80u, 0x3F803F80u, 0x3F803F80u, 0x3F803F80u};

  auto stage = [&](int kt, unsigned short* Ks, unsigned short* Vs) {
    for (int t = 0; t < 4; ++t) {
      const int j = t * 256 + tid;
      const int n = j >> 4, slot = j & 15;
      const int gc = (slot & 8) | ((slot & 7) ^ (n & 7));
      async_cp16(Kb + (size_t)(tokbase + kt * 64 + n) * HID + h * DK + gc * 8,
                 Ks + j * 8);
    }
    for (int t = 0; t < 4; ++t) {
      const int j = t * 256 + tid;
      const int d = j >> 3, slot = j & 7;
      const int gc = slot ^ (d & 7);
      async_cp16(VtG + ((size_t)(bh * DK + d)) * SEQ + kt * 64 + gc * 8,
                 Vs + j * 8);
    }
  };

  for (int phase = 0; phase < 2; ++phase) {
    const int qt = phase ? (31 - bx) : bx;
    const int q0 = qt * 64;

    u32x4 qf[4];
    {
      const unsigned short* qrow =
          Qb + (size_t)(tokbase + q0 + wave * 16 + r) * HID + h * DK;
      for (int kk = 0; kk < 4; ++kk)
        qf[kk] = *(const u32x4*)(qrow + kk * 32 + quad * 8);
    }

    f32x4 o[8] = {};
    float m_i[4], l_i[4];
    for (int v = 0; v < 4; ++v) { m_i[v] = -__builtin_inff(); l_i[v] = 0.f; }

    auto body = [&](const unsigned short* Ks, const unsigned short* Vs, int kt) {
      f32x4 s[4];
      for (int nt = 0; nt < 4; ++nt) {
        f32x4 a = {};
        const int n = nt * 16 + r;
        for (int kk = 0; kk < 4; ++kk) {
          const int c = kk * 4 + quad;
          const int slot = (c & 8) | ((c & 7) ^ (r & 7));
          u32x4 bkf = *(const u32x4*)(Ks + n * 128 + slot * 8);
          a = __builtin_amdgcn_mfma_f32_16x16x32_bf16(
              __builtin_bit_cast(bf16x8, qf[kk]),
              __builtin_bit_cast(bf16x8, bkf), a, 0, 0, 0);
        }
        s[nt] = a;
      }

      if (kt == qt) {
        const int qrow_g = q0 + wave * 16 + quad * 4;
        for (int nt = 0; nt < 4; ++nt) {
          const int col = kt * 64 + nt * 16 + r;
          for (int v = 0; v < 4; ++v)
            if (col > qrow_g + v) s[nt][v] = -__builtin_inff();
        }
      }

      float mx[4];
      for (int v = 0; v < 4; ++v)
        mx[v] = fmaxf(fmaxf(s[0][v], s[1][v]), fmaxf(s[2][v], s[3][v]));
      for (int off = 1; off < 16; off <<= 1)
        for (int v = 0; v < 4; ++v)
          mx[v] = fmaxf(mx[v], __shfl_xor(mx[v], off, 64));

      float alpha[4];
      for (int v = 0; v < 4; ++v) {
        const float mnew = fmaxf(m_i[v], mx[v]);
        alpha[v] = exp2f(m_i[v] - mnew);
        m_i[v] = mnew;
      }

      unsigned short* ps = &Ps[wave][0];
      for (int nt = 0; nt < 4; ++nt) {
        const int chunk = nt * 2 + (r >> 3);
        for (int v = 0; v < 4; ++v) {
          const float p = exp2f(s[nt][v] - m_i[v]);
          const int row = quad * 4 + v;
          const int slot = chunk ^ (row & 7);
          ps[row * 64 + slot * 8 + (r & 7)] = f2bf(p);
        }
      }
      for (int dt = 0; dt < 8; ++dt)
        for (int v = 0; v < 4; ++v)
          o[dt][v] *= alpha[v];
      __asm__ volatile("" ::: "memory");  // keep P writes before P reads

      f32x4 rsacc = {};
      for (int kk2 = 0; kk2 < 2; ++kk2) {
        const int c = kk2 * 4 + quad;
        const int aslot = c ^ (r & 7);
        u32x4 pa = *(const u32x4*)(ps + r * 64 + aslot * 8);
        rsacc = __builtin_amdgcn_mfma_f32_16x16x32_bf16(
            __builtin_bit_cast(bf16x8, pa),
            __builtin_bit_cast(bf16x8, onesv), rsacc, 0, 0, 0);
        for (int dt = 0; dt < 8; ++dt) {
          const int d = dt * 16 + r;
          const int bslot = c ^ (d & 7);
          u32x4 bv = *(const u32x4*)(Vs + d * 64 + bslot * 8);
          o[dt] = __builtin_amdgcn_mfma_f32_16x16x32_bf16(
              __builtin_bit_cast(bf16x8, pa),
              __builtin_bit_cast(bf16x8, bv), o[dt], 0, 0, 0);
        }
      }
      for (int v = 0; v < 4; ++v)
        l_i[v] = l_i[v] * alpha[v] + rsacc[v];
    };

    stage(0, KsA, VsA);
    int kt = 0;
    while (true) {
      __syncthreads();                        // waits on loads from last iter
      if (kt + 1 <= qt) stage(kt + 1, KsB, VsB);
      body(KsA, VsA, kt);
      if (++kt > qt) break;
      __syncthreads();
      if (kt + 1 <= qt) stage(kt + 1, KsA, VsA);
      body(KsB, VsB, kt);
      if (++kt > qt) break;
    }

    float li[4];
    for (int v = 0; v < 4; ++v) li[v] = 1.f / l_i[v];
    for (int dt = 0; dt < 8; ++dt)
      for (int v = 0; v < 4; ++v) {
        const size_t row = (size_t)tokbase + q0 + wave * 16 + quad * 4 + v;
        Ob[row * HID + h * DK + dt * 16 + r] = f2bf(o[dt][v] * li[v]);
      }
    __syncthreads();  // protect K/V buffers before next phase's prologue stage
  }
}

// ---------------- host ------------------------------------------------------
extern "C" void kernel_launch(void* const* d_in, const int* in_sizes, int n_in,
                              void* d_out, int out_size, void* d_ws, size_t ws_size,
                              hipStream_t stream) {
  const float* x  = (const float*)d_in[0];
  const float* fc = (const float*)d_in[1];
  const float* wq = (const float*)d_in[2];
  const float* wk = (const float*)d_in[3];
  const float* wv = (const float*)d_in[4];
  const float* wo = (const float*)d_in[5];
  float* out = (float*)d_out;

  unsigned short* xb  = (unsigned short*)d_ws;     // [4096][2048]
  unsigned short* wqb = xb  + (size_t)NTOK * HID;  // [2048][2048] each
  unsigned short* wkb = wqb + (size_t)HID * HID;
  unsigned short* wvb = wkb + (size_t)HID * HID;
  unsigned short* wob = wvb + (size_t)HID * HID;
  unsigned short* qb  = wob + (size_t)HID * HID;   // [4096][2048]
  unsigned short* kb  = qb  + (size_t)NTOK * HID;
  unsigned short* vtb = kb  + (size_t)NTOK * HID;  // V^T [32*128][2048]
  unsigned short* ab  = vtb + (size_t)NTOK * HID;  // attn out [4096][2048]
  unsigned int*   fcb = (unsigned int*)(ab + (size_t)NTOK * HID);  // [2048*64]

  convert_all_kernel<<<24576 + 512, 256, 0, stream>>>(
      x, wq, wk, wv, wo, fc, xb, wqb, wkb, wvb, wob, fcb);

  gemm_bt_kernel<false><<<dim3(48, 32), 256, 0, stream>>>(
      xb, wqb, wkb, wvb, qb, kb, vtb, nullptr, fcb);

  flash_attn_kernel<<<dim3(16, 32), 256, 0, stream>>>(qb, kb, vtb, ab);

  gemm_bt_kernel<true><<<dim3(16, 32), 256, 0, stream>>>(
      ab, wob, nullptr, nullptr, nullptr, nullptr, nullptr, out, fcb);
}